// Round 15
// baseline (276.144 us; speedup 1.0000x reference)
//
#include <hip/hip_runtime.h>
#include <hip/hip_bf16.h>

// EGCL (EGNN layer): N=384 nodes, V=32 vectors, H=128 feats, U=256 width.
// E = N*(N-1) = 147072 fully-connected edges. f32 in/out, bf16 MFMA compute.
// Edges grouped by RECEIVER r (s=(r+1+j')%N): segment sums are in-block
// reductions; [E,256] intermediates never touch HBM.
// R15 (R14 base): shift computation fully fused into the phi_x MFMA
// epilogue (in-register, direct atomicAdd) -- deletes barrier B7, the
// phix f32 LDS roundtrip, and the 384-thread pass that re-loaded nv[s]
// 6144x/block. Edge barriers 7 -> 6.

#define NN 384
#define VV 32
#define HH 128
#define UU 256
#define MM 64            // edges per block
#define NCHUNK 6         // 6*64 = 384 = 383 edges + 1 pad
#define SS 264           // LDS row stride edge buffers (256-wide, +8 pad)
#define XS 392           // node xs row stride (384-wide, +8 pad)

typedef __bf16 bf16v8 __attribute__((ext_vector_type(8)));
typedef __bf16 bf16v4 __attribute__((ext_vector_type(4)));
typedef float  f32x4  __attribute__((ext_vector_type(4)));
typedef float  f32x16 __attribute__((ext_vector_type(16)));

__device__ __forceinline__ float fast_rcp(float x) { return __builtin_amdgcn_rcpf(x); }
__device__ __forceinline__ float fast_sqrt(float x) { return __builtin_amdgcn_sqrtf(x); }
__device__ __forceinline__ float fast_silu(float v) {
    return v * __builtin_amdgcn_rcpf(1.f + __expf(-v));
}

// ---------------- repack + cvec + accumulator zeroing ----------------------
// blocks [0,212): fmt32 LDS-tiled transpose  P[kt][n][kk]=W[kt*16+kk][n]*s
// blocks [212,372): scalar fmt16 (Wxl, Whl)
// blocks [372,756): cvecg[r][n] = sum_k nf[r][k]*We1[160+k][n]*s288
// blocks [756,888): zero mi[384*256]+shift[384*96] (float4 stores)
__global__ __launch_bounds__(256)
void repack_all(const float* __restrict__ We1, const float* __restrict__ We2,
                const float* __restrict__ Wx1, const float* __restrict__ Wx2,
                const float* __restrict__ Wh1, const float* __restrict__ Wh2,
                const float* __restrict__ Wxl, const float* __restrict__ Whl,
                const float* __restrict__ nf,
                __bf16* __restrict__ we1p, __bf16* __restrict__ we2p,
                __bf16* __restrict__ wx1p, __bf16* __restrict__ wx2p,
                __bf16* __restrict__ wh1p, __bf16* __restrict__ wh2p,
                __bf16* __restrict__ wxlp, __bf16* __restrict__ whlp,
                float* __restrict__ cvecg, float* __restrict__ zbase) {
    const float s288 = 0.05892556509887896f;   // 1/sqrt(288)
    const float s384 = 0.05103103630798288f;   // 1/sqrt(384)
    const float s16  = 0.0625f;
    const int b   = blockIdx.x;
    const int tid = threadIdx.x;

    if (b < 212) {                               // ---- fmt32 transpose tiles
        __shared__ __bf16 T[32 * 72];
        const float* src; __bf16* dst; int tile; float scale;
        if (b < 36)       { src = We1; dst = we1p; tile = b;       scale = s288; }
        else if (b < 68)  { src = We2; dst = we2p; tile = b - 36;  scale = s16;  }
        else if (b < 100) { src = Wx1; dst = wx1p; tile = b - 68;  scale = s16;  }
        else if (b < 132) { src = Wx2; dst = wx2p; tile = b - 100; scale = s16;  }
        else if (b < 180) { src = Wh1; dst = wh1p; tile = b - 132; scale = s384; }
        else              { src = Wh2; dst = wh2p; tile = b - 180; scale = s16;  }
        const int kt0 = tile >> 2, nt0 = tile & 3;
        const int k0 = kt0 * 32, n0 = nt0 * 64;
#pragma unroll
        for (int i = 0; i < 8; ++i) {
            int p = tid + i * 256;
            int k = p >> 6, n = p & 63;
            T[k * 72 + n] = (__bf16)(src[(k0 + k) * 256 + n0 + n] * scale);
        }
        __syncthreads();
        const int ktl = tid >> 7, rem = tid & 127;
        const int n = rem >> 1, kh = rem & 1;
        bf16v8 v;
#pragma unroll
        for (int j = 0; j < 8; ++j)
            v[j] = T[(ktl * 16 + kh * 8 + j) * 72 + n];
        *(bf16v8*)(dst + (kt0 * 2 + ktl) * 4096 + (n0 + n) * 16 + kh * 8) = v;
        return;
    }
    if (b < 372) {      // ---- scalar fmt16: Wxl (8192 el), Whl (32768 el)
        int t = (b - 212) * 256 + tid;
        const float* src; __bf16* dst; int Nout; int idx; float scale;
        if (t < 8192)       { src = Wxl; dst = wxlp; Nout = 32;  idx = t;        scale = 1.0f; }
        else if (t < 40960) { src = Whl; dst = whlp; Nout = 128; idx = t - 8192; scale = s16;  }
        else return;
        int kt  = idx / (Nout * 32);
        int rem = idx - kt * Nout * 32;
        int n   = rem >> 5;
        int kk  = rem & 31;
        dst[idx] = (__bf16)(src[(kt * 32 + kk) * Nout + n] * scale);
        return;
    }
    if (b < 756) {      // ---- cvecg: per-receiver constant term of gemm1
        int r = b - 372;
        float a = 0.f;
#pragma unroll 4
        for (int k = 0; k < 128; ++k)
            a += nf[r * HH + k] * We1[(160 + k) * 256 + tid];
        cvecg[r * UU + tid] = a * s288;
        return;
    }
    // ---- zero accumulators: 33792 float4 = mi + shift ----
    ((f32x4*)zbase)[(b - 756) * 256 + tid] = (f32x4){0.f, 0.f, 0.f, 0.f};
}

// ---- 64x256 GEMM: Y = silu(X @ Wp [+ cinit]), 8 waves, 32x32x16 MFMA ------
template <int KT>
__device__ __forceinline__ void gemm32(const __bf16* X, int xs,
                                       const __bf16* __restrict__ P,
                                       __bf16* Y, int ys,
                                       int wave, int lane, const float* cinit) {
    const int m  = lane & 31;
    const int kh = lane >> 5;
    float iv = cinit ? cinit[wave * 32 + m] : 0.f;
    f32x16 acc0, acc1;
#pragma unroll
    for (int i = 0; i < 16; ++i) { acc0[i] = iv; acc1[i] = iv; }
    const __bf16* xr = X + m * xs + kh * 8;
    const __bf16* pb = P + (wave * 32 + m) * 16 + kh * 8;
    bf16v8 b0 = *(const bf16v8*)(pb);
    bf16v8 b1 = (KT > 1) ? *(const bf16v8*)(pb + 4096) : b0;
#pragma unroll
    for (int kt = 0; kt < KT; ++kt) {
        bf16v8 a0 = *(const bf16v8*)(xr + kt * 16);
        bf16v8 a1 = *(const bf16v8*)(xr + 32 * xs + kt * 16);
        bf16v8 bn = (kt + 2 < KT) ? *(const bf16v8*)(pb + (kt + 2) * 4096) : b0;
        acc0 = __builtin_amdgcn_mfma_f32_32x32x16_bf16(a0, b0, acc0, 0, 0, 0);
        acc1 = __builtin_amdgcn_mfma_f32_32x32x16_bf16(a1, b0, acc1, 0, 0, 0);
        b0 = b1; b1 = bn;
    }
#pragma unroll
    for (int reg = 0; reg < 16; ++reg) {
        int row = (reg & 3) + 8 * (reg >> 2) + 4 * kh;
        Y[row * ys + wave * 32 + m]        = (__bf16)fast_silu(acc0[reg]);
        Y[(32 + row) * ys + wave * 32 + m] = (__bf16)fast_silu(acc1[reg]);
    }
}

// ---- 32x256 GEMM (single m-tile): Y = silu(X @ Wp), 8 waves ---------------
template <int KT>
__device__ __forceinline__ void gemmS(const __bf16* X, int xs,
                                      const __bf16* __restrict__ P,
                                      __bf16* Y, int ys, int wave, int lane) {
    const int m  = lane & 31;
    const int kh = lane >> 5;
    f32x16 acc = {};
    const __bf16* xr = X + m * xs + kh * 8;
    const __bf16* pb = P + (wave * 32 + m) * 16 + kh * 8;
    bf16v8 b0 = *(const bf16v8*)(pb);
    bf16v8 b1 = (KT > 1) ? *(const bf16v8*)(pb + 4096) : b0;
#pragma unroll
    for (int kt = 0; kt < KT; ++kt) {
        bf16v8 a0 = *(const bf16v8*)(xr + kt * 16);
        bf16v8 bn = (kt + 2 < KT) ? *(const bf16v8*)(pb + (kt + 2) * 4096) : b0;
        acc = __builtin_amdgcn_mfma_f32_32x32x16_bf16(a0, b0, acc, 0, 0, 0);
        b0 = b1; b1 = bn;
    }
#pragma unroll
    for (int reg = 0; reg < 16; ++reg) {
        int row = (reg & 3) + 8 * (reg >> 2) + 4 * kh;
        Y[row * ys + wave * 32 + m] = (__bf16)fast_silu(acc[reg]);
    }
}

// --------------------------- fused edge kernel -----------------------------
__global__ __launch_bounds__(512, 4)
void edge_kernel(const float* __restrict__ nv, const float* __restrict__ nf,
                 const __bf16* __restrict__ we1p, const __bf16* __restrict__ we2p,
                 const __bf16* __restrict__ wx1p, const __bf16* __restrict__ wx2p,
                 const __bf16* __restrict__ wxlp, const float* __restrict__ bxl,
                 const float* __restrict__ winf, const float* __restrict__ cvecg,
                 float* __restrict__ shift, float* __restrict__ mi) {
    __shared__ __align__(16) __bf16 Ab[MM * SS];   // ef -> m -> t2
    __shared__ __align__(16) __bf16 Bb[MM * SS];   // h1 -> t1
    __shared__ float gateb[MM];

    const int tid  = threadIdx.x;
    const int wave = tid >> 6;
    const int lane = tid & 63;
    const int col  = lane & 15;
    const int q    = lane >> 4;
    const int r     = blockIdx.y;
    const int chunk = blockIdx.x;
    const int e0    = chunk * MM;

    // ---- stage: len2 (cols 0..31), nf[s] (cols 32..159) ----
#pragma unroll
    for (int p = tid; p < MM * 32; p += 512) {
        int i = p >> 5, v = p & 31;
        int s = r + 1 + e0 + i; if (s >= NN) s -= NN;
        const float* pr = nv + (r * 32 + v) * 3;
        const float* ps = nv + (s * 32 + v) * 3;
        float d0 = pr[0] - ps[0];
        float d1 = pr[1] - ps[1];
        float d2 = pr[2] - ps[2];
        Ab[i * SS + v] = (__bf16)(d0 * d0 + d1 * d1 + d2 * d2);
    }
#pragma unroll
    for (int p = tid; p < MM * 32; p += 512) {
        int i = p >> 5, hc = (p & 31) << 2;
        int s = r + 1 + e0 + i; if (s >= NN) s -= NN;
        float4 fs = *(const float4*)(nf + s * HH + hc);
        bf16v4 bs = { (__bf16)fs.x, (__bf16)fs.y, (__bf16)fs.z, (__bf16)fs.w };
        *(bf16v4*)&Ab[i * SS + 32 + hc] = bs;
    }
    __syncthreads();                                                   // B1

    // ---- h1 = silu(ef @ We1'[0:160] + cvecg[r]) : A -> B ----
    gemm32<10>(Ab, SS, we1p, Bb, SS, wave, lane, cvecg + r * UU);
    __syncthreads();                                                   // B2
    // ---- m = silu(h1 @ We2') : B -> A ----
    gemm32<16>(Bb, SS, we2p, Ab, SS, wave, lane, nullptr);
    __syncthreads();                                                   // B3

    // ---- gate e = sigmoid(m @ Winf / 16); 8-lane shfl reduce ----
    {
        int i = tid >> 3, kq = (tid & 7) * 32;
        const __bf16* mrow = Ab + i * SS + kq;
        const float*  wrow = winf + kq;
        float g = 0.f;
#pragma unroll
        for (int k = 0; k < 32; ++k)
            g += (float)mrow[k] * wrow[k];
        g += __shfl_xor(g, 1);
        g += __shfl_xor(g, 2);
        g += __shfl_xor(g, 4);
        if ((tid & 7) == 0)
            gateb[i] = (e0 + i == NN - 1) ? 0.f     // self-edge pad
                                          : fast_rcp(1.f + __expf(-g * 0.0625f));
    }
    __syncthreads();                                                   // B4

    // ---- m_i partials -> atomicAdd (overlaps gemm3; no barrier) ----
    {
        int c = tid & 255, ih = (tid >> 8) * 32;
        const __bf16* mcol = Ab + ih * SS + c;
        const float*  gp   = gateb + ih;
        float mp = 0.f;
#pragma unroll
        for (int i = 0; i < 32; ++i)
            mp += (float)mcol[i * SS] * gp[i];
        atomicAdd(&mi[r * UU + c], mp);
    }

    // ---- t1 = silu(m @ Wx1'): A -> B ; t2 = silu(t1 @ Wx2'): B -> A ----
    gemm32<16>(Ab, SS, wx1p, Bb, SS, wave, lane, nullptr);
    __syncthreads();                                                   // B5
    gemm32<16>(Bb, SS, wx2p, Ab, SS, wave, lane, nullptr);
    __syncthreads();                                                   // B6

    // ---- phi_x MFMA + shift fused, all in registers -> atomicAdd ----
    // wave: mt=wave>>1 (edge 16-row slice), nt=wave&1 (v half); per lane:
    // v = nt*16+col, edges e = mt*16+q*4+i.
    {
        int mt = wave >> 1, nt = wave & 1;
        int v = nt * 16 + col;
        float bias = bxl[v];
        f32x4 acc = {bias, bias, bias, bias};
        const __bf16* xr = Ab + (mt * 16 + col) * SS + q * 8;
#pragma unroll
        for (int kt = 0; kt < 8; ++kt) {
            bf16v8 a = *(const bf16v8*)(xr + kt * 32);
            bf16v8 b = *(const bf16v8*)(wxlp + kt * 1024 + v * 32 + q * 8);
            acc = __builtin_amdgcn_mfma_f32_16x16x32_bf16(a, b, acc, 0, 0, 0);
        }
        float r0 = nv[(r * 32 + v) * 3 + 0];
        float r1 = nv[(r * 32 + v) * 3 + 1];
        float r2 = nv[(r * 32 + v) * 3 + 2];
        float sp0 = 0.f, sp1 = 0.f, sp2 = 0.f;
#pragma unroll
        for (int i = 0; i < 4; ++i) {
            int e = mt * 16 + q * 4 + i;
            int s = r + 1 + e0 + e; if (s >= NN) s -= NN;
            const float* ps = nv + (s * 32 + v) * 3;
            float d0 = r0 - ps[0], d1 = r1 - ps[1], d2 = r2 - ps[2];
            float len = fast_sqrt(fmaxf(d0 * d0 + d1 * d1 + d2 * d2, 1e-20f));
            float w = acc[i] * fast_rcp(1.f + len);   // self-edge: d=0 -> 0
            sp0 += w * d0; sp1 += w * d1; sp2 += w * d2;
        }
        atomicAdd(&shift[r * 96 + v * 3 + 0], sp0);
        atomicAdd(&shift[r * 96 + v * 3 + 1], sp1);
        atomicAdd(&shift[r * 96 + v * 3 + 2], sp2);
    }
}

// ---------------- node MLP (12 blocks x 32 rows) ---------------------------
__global__ __launch_bounds__(512)
void node_kernel(const float* __restrict__ nv, const float* __restrict__ nf,
                 const __bf16* __restrict__ wh1p, const __bf16* __restrict__ wh2p,
                 const __bf16* __restrict__ whlp,
                 const float* __restrict__ shift, const float* __restrict__ mi,
                 float* __restrict__ out) {
    __shared__ __align__(16) __bf16 xsb[32 * XS];   // [m_i | nf] 32x384
    __shared__ __align__(16) __bf16 h1b[32 * SS];
    __shared__ __align__(16) __bf16 h2b[32 * SS];
    const int tid  = threadIdx.x;
    const int wave = tid >> 6;
    const int lane = tid & 63;
    const int n0   = blockIdx.x * 32;

    // ---- stage xs = [m_i | nf]; vectors_out ----
#pragma unroll
    for (int p = tid; p < 32 * 256; p += 512) {
        int i = p >> 8, c = p & 255;
        xsb[i * XS + c] = (__bf16)mi[(n0 + i) * UU + c];
    }
#pragma unroll
    for (int p = tid; p < 32 * 128; p += 512) {
        int i = p >> 7, c = p & 127;
        xsb[i * XS + 256 + c] = (__bf16)nf[(n0 + i) * HH + c];
    }
#pragma unroll
    for (int p = tid; p < 32 * 96; p += 512) {
        int i = p / 96, j = p - i * 96;
        out[(n0 + i) * 96 + j] = nv[(n0 + i) * 96 + j]
                                 + shift[(n0 + i) * 96 + j] * (1.f / 383.f);
    }
    __syncthreads();

    // ---- h1 = silu(xs @ Wh1') ; h2 = silu(h1 @ Wh2') ----
    gemmS<24>(xsb, XS, wh1p, h1b, SS, wave, lane);
    __syncthreads();
    gemmS<16>(h1b, SS, wh2p, h2b, SS, wave, lane);
    __syncthreads();

    // ---- features_out = h2 @ Whl' + nf  (N=128, 16x16 MFMA, 8 n-tiles) ----
    {
        int col = lane & 15, q = lane >> 4;
        int n = wave * 16 + col;
#pragma unroll
        for (int mt = 0; mt < 2; ++mt) {
            f32x4 acc = {0.f, 0.f, 0.f, 0.f};
            const __bf16* xr = h2b + (mt * 16 + col) * SS + q * 8;
#pragma unroll
            for (int kt = 0; kt < 8; ++kt) {
                bf16v8 a = *(const bf16v8*)(xr + kt * 32);
                bf16v8 b = *(const bf16v8*)(whlp + kt * 4096 + n * 32 + q * 8);
                acc = __builtin_amdgcn_mfma_f32_16x16x32_bf16(a, b, acc, 0, 0, 0);
            }
#pragma unroll
            for (int i = 0; i < 4; ++i) {
                int row = n0 + mt * 16 + q * 4 + i;
                out[NN * 96 + row * HH + n] = acc[i] + nf[row * HH + n];
            }
        }
    }
}

// ------------------------------- launcher ----------------------------------
extern "C" void kernel_launch(void* const* d_in, const int* in_sizes, int n_in,
                              void* d_out, int out_size, void* d_ws, size_t ws_size,
                              hipStream_t stream) {
    const float* nv   = (const float*)d_in[0];
    const float* nf   = (const float*)d_in[1];
    const float* We1  = (const float*)d_in[2];
    const float* We2  = (const float*)d_in[3];
    const float* Wx1  = (const float*)d_in[4];
    const float* Wx2  = (const float*)d_in[5];
    const float* Wxl  = (const float*)d_in[6];
    const float* bxl  = (const float*)d_in[7];
    const float* Winf = (const float*)d_in[8];
    const float* Wh1  = (const float*)d_in[9];
    const float* Wh2  = (const float*)d_in[10];
    const float* Whl  = (const float*)d_in[11];
    float* out = (float*)d_out;

    char* ws = (char*)d_ws;
    float*  mi     = (float*)ws;                        // 384*256*4 = 393216
    float*  shift  = (float*)(ws + 393216);             // 384*96*4  = 147456
    float*  cvecg  = (float*)(ws + 540672);             // 384*256*4 = 393216
    __bf16* we1p   = (__bf16*)(ws + 933888);            // 147456
    __bf16* we2p   = (__bf16*)(ws + 1081344);           // 131072
    __bf16* wx1p   = (__bf16*)(ws + 1212416);           // 131072
    __bf16* wx2p   = (__bf16*)(ws + 1343488);           // 131072
    __bf16* wh1p   = (__bf16*)(ws + 1474560);           // 196608
    __bf16* wh2p   = (__bf16*)(ws + 1671168);           // 131072
    __bf16* wxlp   = (__bf16*)(ws + 1802240);           // 16384
    __bf16* whlp   = (__bf16*)(ws + 1818624);           // 65536

    repack_all<<<dim3(888), 256, 0, stream>>>(We1, We2, Wx1, Wx2, Wh1, Wh2, Wxl, Whl,
                                              nf, we1p, we2p, wx1p, wx2p,
                                              wh1p, wh2p, wxlp, whlp, cvecg, mi);

    edge_kernel<<<dim3(NCHUNK, NN), 512, 0, stream>>>(nv, nf, we1p, we2p, wx1p, wx2p,
                                                      wxlp, bxl, Winf, cvecg,
                                                      shift, mi);
    node_kernel<<<dim3(12), 512, 0, stream>>>(nv, nf, wh1p, wh2p, whlp,
                                              shift, mi, out);
}

// Round 16
// 200.761 us; speedup vs baseline: 1.3755x; 1.3755x over previous
//
#include <hip/hip_runtime.h>
#include <hip/hip_bf16.h>

// EGCL (EGNN layer): N=384 nodes, V=32 vectors, H=128 feats, U=256 width.
// E = N*(N-1) = 147072 fully-connected edges. f32 in/out, bf16 MFMA compute.
// Edges grouped by RECEIVER r (s=(r+1+j')%N): segment sums are in-block
// reductions; [E,256] intermediates never touch HBM.
// R16 (R14 base): shift fused into phi_x epilogue IN REGISTERS (like R15)
// but reduced through a 3KB LDS array -> 96 atomics/block (R14: 384,
// R15: 1536 -- R15's same-address device atomics streamed 56MB to HBM and
// paced the kernel). Deletes R14's Bf roundtrip + nv re-load pass.

#define NN 384
#define VV 32
#define HH 128
#define UU 256
#define MM 64            // edges per block
#define NCHUNK 6         // 6*64 = 384 = 383 edges + 1 pad
#define SS 264           // LDS row stride edge buffers (256-wide, +8 pad)
#define XS 392           // node xs row stride (384-wide, +8 pad)

typedef __bf16 bf16v8 __attribute__((ext_vector_type(8)));
typedef __bf16 bf16v4 __attribute__((ext_vector_type(4)));
typedef float  f32x4  __attribute__((ext_vector_type(4)));
typedef float  f32x16 __attribute__((ext_vector_type(16)));

__device__ __forceinline__ float fast_rcp(float x) { return __builtin_amdgcn_rcpf(x); }
__device__ __forceinline__ float fast_sqrt(float x) { return __builtin_amdgcn_sqrtf(x); }
__device__ __forceinline__ float fast_silu(float v) {
    return v * __builtin_amdgcn_rcpf(1.f + __expf(-v));
}

// ---------------- repack + cvec + accumulator zeroing ----------------------
// blocks [0,212): fmt32 LDS-tiled transpose  P[kt][n][kk]=W[kt*16+kk][n]*s
// blocks [212,372): scalar fmt16 (Wxl, Whl)
// blocks [372,756): cvecg[r][n] = sum_k nf[r][k]*We1[160+k][n]*s288
// blocks [756,888): zero mi[384*256]+shift[384*96] (float4 stores)
__global__ __launch_bounds__(256)
void repack_all(const float* __restrict__ We1, const float* __restrict__ We2,
                const float* __restrict__ Wx1, const float* __restrict__ Wx2,
                const float* __restrict__ Wh1, const float* __restrict__ Wh2,
                const float* __restrict__ Wxl, const float* __restrict__ Whl,
                const float* __restrict__ nf,
                __bf16* __restrict__ we1p, __bf16* __restrict__ we2p,
                __bf16* __restrict__ wx1p, __bf16* __restrict__ wx2p,
                __bf16* __restrict__ wh1p, __bf16* __restrict__ wh2p,
                __bf16* __restrict__ wxlp, __bf16* __restrict__ whlp,
                float* __restrict__ cvecg, float* __restrict__ zbase) {
    const float s288 = 0.05892556509887896f;   // 1/sqrt(288)
    const float s384 = 0.05103103630798288f;   // 1/sqrt(384)
    const float s16  = 0.0625f;
    const int b   = blockIdx.x;
    const int tid = threadIdx.x;

    if (b < 212) {                               // ---- fmt32 transpose tiles
        __shared__ __bf16 T[32 * 72];
        const float* src; __bf16* dst; int tile; float scale;
        if (b < 36)       { src = We1; dst = we1p; tile = b;       scale = s288; }
        else if (b < 68)  { src = We2; dst = we2p; tile = b - 36;  scale = s16;  }
        else if (b < 100) { src = Wx1; dst = wx1p; tile = b - 68;  scale = s16;  }
        else if (b < 132) { src = Wx2; dst = wx2p; tile = b - 100; scale = s16;  }
        else if (b < 180) { src = Wh1; dst = wh1p; tile = b - 132; scale = s384; }
        else              { src = Wh2; dst = wh2p; tile = b - 180; scale = s16;  }
        const int kt0 = tile >> 2, nt0 = tile & 3;
        const int k0 = kt0 * 32, n0 = nt0 * 64;
#pragma unroll
        for (int i = 0; i < 8; ++i) {
            int p = tid + i * 256;
            int k = p >> 6, n = p & 63;
            T[k * 72 + n] = (__bf16)(src[(k0 + k) * 256 + n0 + n] * scale);
        }
        __syncthreads();
        const int ktl = tid >> 7, rem = tid & 127;
        const int n = rem >> 1, kh = rem & 1;
        bf16v8 v;
#pragma unroll
        for (int j = 0; j < 8; ++j)
            v[j] = T[(ktl * 16 + kh * 8 + j) * 72 + n];
        *(bf16v8*)(dst + (kt0 * 2 + ktl) * 4096 + (n0 + n) * 16 + kh * 8) = v;
        return;
    }
    if (b < 372) {      // ---- scalar fmt16: Wxl (8192 el), Whl (32768 el)
        int t = (b - 212) * 256 + tid;
        const float* src; __bf16* dst; int Nout; int idx; float scale;
        if (t < 8192)       { src = Wxl; dst = wxlp; Nout = 32;  idx = t;        scale = 1.0f; }
        else if (t < 40960) { src = Whl; dst = whlp; Nout = 128; idx = t - 8192; scale = s16;  }
        else return;
        int kt  = idx / (Nout * 32);
        int rem = idx - kt * Nout * 32;
        int n   = rem >> 5;
        int kk  = rem & 31;
        dst[idx] = (__bf16)(src[(kt * 32 + kk) * Nout + n] * scale);
        return;
    }
    if (b < 756) {      // ---- cvecg: per-receiver constant term of gemm1
        int r = b - 372;
        float a = 0.f;
#pragma unroll 4
        for (int k = 0; k < 128; ++k)
            a += nf[r * HH + k] * We1[(160 + k) * 256 + tid];
        cvecg[r * UU + tid] = a * s288;
        return;
    }
    // ---- zero accumulators: 33792 float4 = mi + shift ----
    ((f32x4*)zbase)[(b - 756) * 256 + tid] = (f32x4){0.f, 0.f, 0.f, 0.f};
}

// ---- 64x256 GEMM: Y = silu(X @ Wp [+ cinit]), 8 waves, 32x32x16 MFMA ------
template <int KT>
__device__ __forceinline__ void gemm32(const __bf16* X, int xs,
                                       const __bf16* __restrict__ P,
                                       __bf16* Y, int ys,
                                       int wave, int lane, const float* cinit) {
    const int m  = lane & 31;
    const int kh = lane >> 5;
    float iv = cinit ? cinit[wave * 32 + m] : 0.f;
    f32x16 acc0, acc1;
#pragma unroll
    for (int i = 0; i < 16; ++i) { acc0[i] = iv; acc1[i] = iv; }
    const __bf16* xr = X + m * xs + kh * 8;
    const __bf16* pb = P + (wave * 32 + m) * 16 + kh * 8;
    bf16v8 b0 = *(const bf16v8*)(pb);
    bf16v8 b1 = (KT > 1) ? *(const bf16v8*)(pb + 4096) : b0;
#pragma unroll
    for (int kt = 0; kt < KT; ++kt) {
        bf16v8 a0 = *(const bf16v8*)(xr + kt * 16);
        bf16v8 a1 = *(const bf16v8*)(xr + 32 * xs + kt * 16);
        bf16v8 bn = (kt + 2 < KT) ? *(const bf16v8*)(pb + (kt + 2) * 4096) : b0;
        acc0 = __builtin_amdgcn_mfma_f32_32x32x16_bf16(a0, b0, acc0, 0, 0, 0);
        acc1 = __builtin_amdgcn_mfma_f32_32x32x16_bf16(a1, b0, acc1, 0, 0, 0);
        b0 = b1; b1 = bn;
    }
#pragma unroll
    for (int reg = 0; reg < 16; ++reg) {
        int row = (reg & 3) + 8 * (reg >> 2) + 4 * kh;
        Y[row * ys + wave * 32 + m]        = (__bf16)fast_silu(acc0[reg]);
        Y[(32 + row) * ys + wave * 32 + m] = (__bf16)fast_silu(acc1[reg]);
    }
}

// ---- 32x256 GEMM (single m-tile): Y = silu(X @ Wp), 8 waves ---------------
template <int KT>
__device__ __forceinline__ void gemmS(const __bf16* X, int xs,
                                      const __bf16* __restrict__ P,
                                      __bf16* Y, int ys, int wave, int lane) {
    const int m  = lane & 31;
    const int kh = lane >> 5;
    f32x16 acc = {};
    const __bf16* xr = X + m * xs + kh * 8;
    const __bf16* pb = P + (wave * 32 + m) * 16 + kh * 8;
    bf16v8 b0 = *(const bf16v8*)(pb);
    bf16v8 b1 = (KT > 1) ? *(const bf16v8*)(pb + 4096) : b0;
#pragma unroll
    for (int kt = 0; kt < KT; ++kt) {
        bf16v8 a0 = *(const bf16v8*)(xr + kt * 16);
        bf16v8 bn = (kt + 2 < KT) ? *(const bf16v8*)(pb + (kt + 2) * 4096) : b0;
        acc = __builtin_amdgcn_mfma_f32_32x32x16_bf16(a0, b0, acc, 0, 0, 0);
        b0 = b1; b1 = bn;
    }
#pragma unroll
    for (int reg = 0; reg < 16; ++reg) {
        int row = (reg & 3) + 8 * (reg >> 2) + 4 * kh;
        Y[row * ys + wave * 32 + m] = (__bf16)fast_silu(acc[reg]);
    }
}

// --------------------------- fused edge kernel -----------------------------
__global__ __launch_bounds__(512, 4)
void edge_kernel(const float* __restrict__ nv, const float* __restrict__ nf,
                 const __bf16* __restrict__ we1p, const __bf16* __restrict__ we2p,
                 const __bf16* __restrict__ wx1p, const __bf16* __restrict__ wx2p,
                 const __bf16* __restrict__ wxlp, const float* __restrict__ bxl,
                 const float* __restrict__ winf, const float* __restrict__ cvecg,
                 float* __restrict__ shift, float* __restrict__ mi) {
    __shared__ __align__(16) __bf16 Ab[MM * SS];   // ef -> m -> t2
    __shared__ __align__(16) __bf16 Bb[MM * SS];   // h1 -> t1
    __shared__ float gateb[MM];
    __shared__ float sred[32 * 24];                // [v][group(8)][c(3)]

    const int tid  = threadIdx.x;
    const int wave = tid >> 6;
    const int lane = tid & 63;
    const int col  = lane & 15;
    const int q    = lane >> 4;
    const int r     = blockIdx.y;
    const int chunk = blockIdx.x;
    const int e0    = chunk * MM;

    // ---- stage: len2 (cols 0..31), nf[s] (cols 32..159) ----
#pragma unroll
    for (int p = tid; p < MM * 32; p += 512) {
        int i = p >> 5, v = p & 31;
        int s = r + 1 + e0 + i; if (s >= NN) s -= NN;
        const float* pr = nv + (r * 32 + v) * 3;
        const float* ps = nv + (s * 32 + v) * 3;
        float d0 = pr[0] - ps[0];
        float d1 = pr[1] - ps[1];
        float d2 = pr[2] - ps[2];
        Ab[i * SS + v] = (__bf16)(d0 * d0 + d1 * d1 + d2 * d2);
    }
#pragma unroll
    for (int p = tid; p < MM * 32; p += 512) {
        int i = p >> 5, hc = (p & 31) << 2;
        int s = r + 1 + e0 + i; if (s >= NN) s -= NN;
        float4 fs = *(const float4*)(nf + s * HH + hc);
        bf16v4 bs = { (__bf16)fs.x, (__bf16)fs.y, (__bf16)fs.z, (__bf16)fs.w };
        *(bf16v4*)&Ab[i * SS + 32 + hc] = bs;
    }
    __syncthreads();                                                   // B1

    // ---- h1 = silu(ef @ We1'[0:160] + cvecg[r]) : A -> B ----
    gemm32<10>(Ab, SS, we1p, Bb, SS, wave, lane, cvecg + r * UU);
    __syncthreads();                                                   // B2
    // ---- m = silu(h1 @ We2') : B -> A ----
    gemm32<16>(Bb, SS, we2p, Ab, SS, wave, lane, nullptr);
    __syncthreads();                                                   // B3

    // ---- gate e = sigmoid(m @ Winf / 16); 8-lane shfl reduce ----
    {
        int i = tid >> 3, kq = (tid & 7) * 32;
        const __bf16* mrow = Ab + i * SS + kq;
        const float*  wrow = winf + kq;
        float g = 0.f;
#pragma unroll
        for (int k = 0; k < 32; ++k)
            g += (float)mrow[k] * wrow[k];
        g += __shfl_xor(g, 1);
        g += __shfl_xor(g, 2);
        g += __shfl_xor(g, 4);
        if ((tid & 7) == 0)
            gateb[i] = (e0 + i == NN - 1) ? 0.f     // self-edge pad
                                          : fast_rcp(1.f + __expf(-g * 0.0625f));
    }
    __syncthreads();                                                   // B4

    // ---- m_i partials -> atomicAdd (overlaps gemm3; no barrier) ----
    {
        int c = tid & 255, ih = (tid >> 8) * 32;
        const __bf16* mcol = Ab + ih * SS + c;
        const float*  gp   = gateb + ih;
        float mp = 0.f;
#pragma unroll
        for (int i = 0; i < 32; ++i)
            mp += (float)mcol[i * SS] * gp[i];
        atomicAdd(&mi[r * UU + c], mp);
    }

    // ---- t1 = silu(m @ Wx1'): A -> B ; t2 = silu(t1 @ Wx2'): B -> A ----
    gemm32<16>(Ab, SS, wx1p, Bb, SS, wave, lane, nullptr);
    __syncthreads();                                                   // B5
    gemm32<16>(Bb, SS, wx2p, Ab, SS, wave, lane, nullptr);
    __syncthreads();                                                   // B6

    // ---- phi_x MFMA + shift in registers -> 3KB LDS partials ----
    // per lane: v = nt*16+col, edges e = mt*16+q*4+i, group g = mt*4+q.
    {
        int mt = wave >> 1, nt = wave & 1;
        int v = nt * 16 + col;
        float bias = bxl[v];
        f32x4 acc = {bias, bias, bias, bias};
        const __bf16* xr = Ab + (mt * 16 + col) * SS + q * 8;
#pragma unroll
        for (int kt = 0; kt < 8; ++kt) {
            bf16v8 a = *(const bf16v8*)(xr + kt * 32);
            bf16v8 b = *(const bf16v8*)(wxlp + kt * 1024 + v * 32 + q * 8);
            acc = __builtin_amdgcn_mfma_f32_16x16x32_bf16(a, b, acc, 0, 0, 0);
        }
        float r0 = nv[(r * 32 + v) * 3 + 0];
        float r1 = nv[(r * 32 + v) * 3 + 1];
        float r2 = nv[(r * 32 + v) * 3 + 2];
        float sp0 = 0.f, sp1 = 0.f, sp2 = 0.f;
#pragma unroll
        for (int i = 0; i < 4; ++i) {
            int e = mt * 16 + q * 4 + i;
            int s = r + 1 + e0 + e; if (s >= NN) s -= NN;
            const float* ps = nv + (s * 32 + v) * 3;
            float d0 = r0 - ps[0], d1 = r1 - ps[1], d2 = r2 - ps[2];
            float len = fast_sqrt(fmaxf(d0 * d0 + d1 * d1 + d2 * d2, 1e-20f));
            float w = acc[i] * fast_rcp(1.f + len);   // self-edge: d=0 -> 0
            sp0 += w * d0; sp1 += w * d1; sp2 += w * d2;
        }
        int g = mt * 4 + q;
        sred[v * 24 + g * 3 + 0] = sp0;
        sred[v * 24 + g * 3 + 1] = sp1;
        sred[v * 24 + g * 3 + 2] = sp2;
    }
    __syncthreads();                                                   // B7

    // ---- reduce 8 groups -> one atomic per (v,c): 96 atomics/block ----
    if (tid < 96) {
        int v = tid / 3, c = tid - v * 3;
        float s = 0.f;
#pragma unroll
        for (int g = 0; g < 8; ++g)
            s += sred[v * 24 + g * 3 + c];
        atomicAdd(&shift[r * 96 + tid], s);
    }
}

// ---------------- node MLP (12 blocks x 32 rows) ---------------------------
__global__ __launch_bounds__(512)
void node_kernel(const float* __restrict__ nv, const float* __restrict__ nf,
                 const __bf16* __restrict__ wh1p, const __bf16* __restrict__ wh2p,
                 const __bf16* __restrict__ whlp,
                 const float* __restrict__ shift, const float* __restrict__ mi,
                 float* __restrict__ out) {
    __shared__ __align__(16) __bf16 xsb[32 * XS];   // [m_i | nf] 32x384
    __shared__ __align__(16) __bf16 h1b[32 * SS];
    __shared__ __align__(16) __bf16 h2b[32 * SS];
    const int tid  = threadIdx.x;
    const int wave = tid >> 6;
    const int lane = tid & 63;
    const int n0   = blockIdx.x * 32;

    // ---- stage xs = [m_i | nf]; vectors_out ----
#pragma unroll
    for (int p = tid; p < 32 * 256; p += 512) {
        int i = p >> 8, c = p & 255;
        xsb[i * XS + c] = (__bf16)mi[(n0 + i) * UU + c];
    }
#pragma unroll
    for (int p = tid; p < 32 * 128; p += 512) {
        int i = p >> 7, c = p & 127;
        xsb[i * XS + 256 + c] = (__bf16)nf[(n0 + i) * HH + c];
    }
#pragma unroll
    for (int p = tid; p < 32 * 96; p += 512) {
        int i = p / 96, j = p - i * 96;
        out[(n0 + i) * 96 + j] = nv[(n0 + i) * 96 + j]
                                 + shift[(n0 + i) * 96 + j] * (1.f / 383.f);
    }
    __syncthreads();

    // ---- h1 = silu(xs @ Wh1') ; h2 = silu(h1 @ Wh2') ----
    gemmS<24>(xsb, XS, wh1p, h1b, SS, wave, lane);
    __syncthreads();
    gemmS<16>(h1b, SS, wh2p, h2b, SS, wave, lane);
    __syncthreads();

    // ---- features_out = h2 @ Whl' + nf  (N=128, 16x16 MFMA, 8 n-tiles) ----
    {
        int col = lane & 15, q = lane >> 4;
        int n = wave * 16 + col;
#pragma unroll
        for (int mt = 0; mt < 2; ++mt) {
            f32x4 acc = {0.f, 0.f, 0.f, 0.f};
            const __bf16* xr = h2b + (mt * 16 + col) * SS + q * 8;
#pragma unroll
            for (int kt = 0; kt < 8; ++kt) {
                bf16v8 a = *(const bf16v8*)(xr + kt * 32);
                bf16v8 b = *(const bf16v8*)(whlp + kt * 4096 + n * 32 + q * 8);
                acc = __builtin_amdgcn_mfma_f32_16x16x32_bf16(a, b, acc, 0, 0, 0);
            }
#pragma unroll
            for (int i = 0; i < 4; ++i) {
                int row = n0 + mt * 16 + q * 4 + i;
                out[NN * 96 + row * HH + n] = acc[i] + nf[row * HH + n];
            }
        }
    }
}

// ------------------------------- launcher ----------------------------------
extern "C" void kernel_launch(void* const* d_in, const int* in_sizes, int n_in,
                              void* d_out, int out_size, void* d_ws, size_t ws_size,
                              hipStream_t stream) {
    const float* nv   = (const float*)d_in[0];
    const float* nf   = (const float*)d_in[1];
    const float* We1  = (const float*)d_in[2];
    const float* We2  = (const float*)d_in[3];
    const float* Wx1  = (const float*)d_in[4];
    const float* Wx2  = (const float*)d_in[5];
    const float* Wxl  = (const float*)d_in[6];
    const float* bxl  = (const float*)d_in[7];
    const float* Winf = (const float*)d_in[8];
    const float* Wh1  = (const float*)d_in[9];
    const float* Wh2  = (const float*)d_in[10];
    const float* Whl  = (const float*)d_in[11];
    float* out = (float*)d_out;

    char* ws = (char*)d_ws;
    float*  mi     = (float*)ws;                        // 384*256*4 = 393216
    float*  shift  = (float*)(ws + 393216);             // 384*96*4  = 147456
    float*  cvecg  = (float*)(ws + 540672);             // 384*256*4 = 393216
    __bf16* we1p   = (__bf16*)(ws + 933888);            // 147456
    __bf16* we2p   = (__bf16*)(ws + 1081344);           // 131072
    __bf16* wx1p   = (__bf16*)(ws + 1212416);           // 131072
    __bf16* wx2p   = (__bf16*)(ws + 1343488);           // 131072
    __bf16* wh1p   = (__bf16*)(ws + 1474560);           // 196608
    __bf16* wh2p   = (__bf16*)(ws + 1671168);           // 131072
    __bf16* wxlp   = (__bf16*)(ws + 1802240);           // 16384
    __bf16* whlp   = (__bf16*)(ws + 1818624);           // 65536

    repack_all<<<dim3(888), 256, 0, stream>>>(We1, We2, Wx1, Wx2, Wh1, Wh2, Wxl, Whl,
                                              nf, we1p, we2p, wx1p, wx2p,
                                              wh1p, wh2p, wxlp, whlp, cvecg, mi);

    edge_kernel<<<dim3(NCHUNK, NN), 512, 0, stream>>>(nv, nf, we1p, we2p, wx1p, wx2p,
                                                      wxlp, bxl, Winf, cvecg,
                                                      shift, mi);
    node_kernel<<<dim3(12), 512, 0, stream>>>(nv, nf, wh1p, wh2p, whlp,
                                              shift, mi, out);
}